// Round 5
// baseline (1198.963 us; speedup 1.0000x reference)
//
#include <hip/hip_runtime.h>
#include <math.h>

// GCN 2-layer. R14: SPLIT=8 balance + fused epilogues via last-block fixup.
// R13 (151us) showed launches/partials are minor (~5us); its fused kernels
// launch nb=391 blocks on 256 CUs -> all co-resident, half the CUs carry 2
// blocks => ~1.31x stretch on every edge pass. R14 restores SPLIT=8 (3128
// blocks, dynamic refill, ~5% tail) and replaces R11's combine KERNELS with
// split-K-style in-kernel fixup: each sub-block writes its partial (plain
// stores, exclusive lines), __threadfence (device release), atomicAdd done;
// the 8th block acquires and runs the epilogue. k_bin: EPT=4 (1563 blocks).
// Predict 151 -> ~118-130us. If ~150, imbalance refuted -> mega-kernel next.

#define NPB 256        // nodes per bucket (power of 2)
#define SHIFT 8        // log2(NPB)
#define NB_MAX 512     // max buckets supported by LDS arrays in k_bin
#define SPLIT 8        // sub-blocks per bucket in partial kernels
#define T1 512         // threads per block in k_bin
#define EPT 4          // edges staged per thread in k_bin (tile = 2048 edges)
#define T2 256         // threads per block in edge-pass kernels

#define FSCALE 1024.0f     // fixed-point scale (2^10)
#define FBIAS  8192        // per-addend bias (2^13)
#define FMASK  0x1FFFFFu   // 21-bit field mask

static __device__ __forceinline__ long long load_idx(const void* edges, long long pos, int is64) {
    if (is64) return ((const long long*)edges)[pos];
    return (long long)((const int*)edges)[pos];
}

static __device__ __forceinline__ unsigned long long pack3(float x, float y, float z) {
    unsigned long long e0 = (unsigned)(__float2int_rn(x * FSCALE) + FBIAS);
    unsigned long long e1 = (unsigned)(__float2int_rn(y * FSCALE) + FBIAS);
    unsigned long long e2 = (unsigned)(__float2int_rn(z * FSCALE) + FBIAS);
    return e0 | (e1 << 21) | (e2 << 42);
}

// zero cursors + done counters + dtype-detect flag
__global__ void k_zf(int* cursor, int* done, int nb, const int* e32, int* flag) {
    int i = blockIdx.x * blockDim.x + threadIdx.x;
    if (i < nb) cursor[i] = 0;
    if (i < 3 * nb) done[i] = 0;
    if (i == 0) {
        int is64 = 1;
        for (int k = 0; k < 16; ++k)
            if (e32[2 * k + 1] != 0) { is64 = 0; break; }
        *flag = is64;
    }
}

// Register-staged binning: ONE pass over the edge list; 1 LDS atomic/edge
// (the histogram atomic's return value doubles as the placement rank).
__global__ void k_bin(const void* edges, const int* __restrict__ flag,
                      int* __restrict__ cursor, unsigned int* __restrict__ bin,
                      long long E, int nb, int cap) {
    __shared__ int hist[NB_MAX];
    __shared__ int base[NB_MAX];
    const int tid = threadIdx.x;
    for (int b = tid; b < nb; b += T1) hist[b] = 0;
    __syncthreads();

    const int is64 = *flag;
    const long long start = (long long)blockIdx.x * ((long long)T1 * EPT);
    unsigned es[EPT], ed[EPT];
    int rank[EPT];

    if (is64) {
        const long long* e64 = (const long long*)edges;
#pragma unroll
        for (int j = 0; j < EPT; ++j) {
            long long e = start + j * T1 + tid;
            if (e < E) { es[j] = (unsigned)e64[e]; ed[j] = (unsigned)e64[E + e]; }
            else ed[j] = 0xFFFFFFFFu;
        }
    } else {
        const int* e32 = (const int*)edges;
#pragma unroll
        for (int j = 0; j < EPT; ++j) {
            long long e = start + j * T1 + tid;
            if (e < E) { es[j] = (unsigned)e32[e]; ed[j] = (unsigned)e32[E + e]; }
            else ed[j] = 0xFFFFFFFFu;
        }
    }

#pragma unroll
    for (int j = 0; j < EPT; ++j)
        if (ed[j] != 0xFFFFFFFFu)
            rank[j] = atomicAdd(&hist[ed[j] >> SHIFT], 1);
    __syncthreads();

    for (int b = tid; b < nb; b += T1) {
        int h = hist[b];
        base[b] = h ? atomicAdd(&cursor[b], h) : 0;
    }
    __syncthreads();

#pragma unroll
    for (int j = 0; j < EPT; ++j) {
        if (ed[j] == 0xFFFFFFFFu) continue;
        int bk = (int)(ed[j] >> SHIFT);
        int off = base[bk] + rank[j];
        if (off < cap)
            bin[(long long)bk * cap + off] = ((ed[j] & (NPB - 1)) << 17) | es[j];
    }
}

static __device__ __forceinline__ void sub_range(int cnt, int sub, int* lo, int* hi) {
    int l = (int)(((long long)cnt * sub / SPLIT) & ~3LL);
    int h = (sub == SPLIT - 1) ? cnt : (int)(((long long)cnt * (sub + 1) / SPLIT) & ~3LL);
    *lo = l; *hi = h;
}

// ---- degree pass with last-block fixup (dinv + xs epilogue in-kernel) ----
__global__ void k_degF2(const unsigned int* __restrict__ bin, const int* __restrict__ cursor,
                        const float* __restrict__ x, int* __restrict__ part,
                        int* __restrict__ done, float* __restrict__ dinv,
                        float4* __restrict__ xs, int cap, int n) {
    __shared__ int dcnt[NPB];
    __shared__ int lastFlag;
    const int tid = threadIdx.x;
    dcnt[tid] = 0;
    __syncthreads();
    const int bk = blockIdx.x >> 3;
    const int sub = blockIdx.x & (SPLIT - 1);
    const int cnt = min(cursor[bk], cap);
    int lo, hi; sub_range(cnt, sub, &lo, &hi);
    const unsigned int* bp = bin + (long long)bk * cap;
    const int len = hi - lo, nvec = len >> 2;
    const uint4* bp4 = (const uint4*)(bp + lo);
    for (int v = tid; v < nvec; v += T2) {
        uint4 q = bp4[v];
        atomicAdd(&dcnt[q.x >> 17], 1);
        atomicAdd(&dcnt[q.y >> 17], 1);
        atomicAdd(&dcnt[q.z >> 17], 1);
        atomicAdd(&dcnt[q.w >> 17], 1);
    }
    for (int k = lo + (nvec << 2) + tid; k < hi; k += T2)
        atomicAdd(&dcnt[bp[k] >> 17], 1);
    __syncthreads();
    part[(long long)blockIdx.x * NPB + tid] = dcnt[tid];
    __threadfence();                               // release partials
    if (tid == 0) lastFlag = (atomicAdd(&done[bk], 1) == SPLIT - 1);
    __syncthreads();
    if (!lastFlag) return;
    __threadfence();                               // acquire others' partials
    const int i = bk * NPB + tid;
    if (i >= n) return;
    const volatile int* vp = part;
    int degE = 0;
#pragma unroll
    for (int s = 0; s < SPLIT; ++s)
        degE += vp[(long long)(bk * SPLIT + s) * NPB + tid];
    float di = rsqrtf((float)degE + 1.0f);
    dinv[i] = di;
    xs[i] = make_float4(x[3 * i] * di, x[3 * i + 1] * di, x[3 * i + 2] * di, (float)degE);
}

// ---- layer 1 with last-block fixup (decode + MLP epilogue in-kernel) ----
__global__ void k_agg1F2(const unsigned int* __restrict__ bin, const int* __restrict__ cursor,
                         const float4* __restrict__ xs, const float* __restrict__ dinv,
                         unsigned long long* __restrict__ part, int* __restrict__ done,
                         const float* __restrict__ W1, const float* __restrict__ b1,
                         const float* __restrict__ W2, float* __restrict__ gs,
                         int cap, int n) {
    __shared__ unsigned long long acc[NPB];
    __shared__ int lastFlag;
    const int tid = threadIdx.x;
    acc[tid] = 0ull;
    __syncthreads();
    const int bk = blockIdx.x >> 3;
    const int sub = blockIdx.x & (SPLIT - 1);
    const int cnt = min(cursor[bk], cap);
    int lo, hi; sub_range(cnt, sub, &lo, &hi);
    const unsigned int* bp = bin + (long long)bk * cap;
    const int len = hi - lo, nvec = len >> 2;
    const uint4* bp4 = (const uint4*)(bp + lo);
    for (int v = tid; v < nvec; v += T2) {
        uint4 q = bp4[v];
        float4 v0 = xs[q.x & 0x1FFFFu];
        float4 v1 = xs[q.y & 0x1FFFFu];
        float4 v2 = xs[q.z & 0x1FFFFu];
        float4 v3 = xs[q.w & 0x1FFFFu];
        atomicAdd(&acc[q.x >> 17], pack3(v0.x, v0.y, v0.z));
        atomicAdd(&acc[q.y >> 17], pack3(v1.x, v1.y, v1.z));
        atomicAdd(&acc[q.z >> 17], pack3(v2.x, v2.y, v2.z));
        atomicAdd(&acc[q.w >> 17], pack3(v3.x, v3.y, v3.z));
    }
    for (int k = lo + (nvec << 2) + tid; k < hi; k += T2) {
        unsigned p = bp[k];
        float4 v = xs[p & 0x1FFFFu];
        atomicAdd(&acc[p >> 17], pack3(v.x, v.y, v.z));
    }
    __syncthreads();
    part[(long long)blockIdx.x * NPB + tid] = acc[tid];
    __threadfence();
    if (tid == 0) lastFlag = (atomicAdd(&done[bk], 1) == SPLIT - 1);
    __syncthreads();
    if (!lastFlag) return;
    __threadfence();
    const int i = bk * NPB + tid;
    if (i >= n) return;
    const volatile unsigned long long* vp = part;
    int f0 = 0, f1 = 0, f2 = 0;
#pragma unroll
    for (int s = 0; s < SPLIT; ++s) {
        unsigned long long p = vp[(long long)(bk * SPLIT + s) * NPB + tid];
        f0 += (int)(p & FMASK);
        f1 += (int)((p >> 21) & FMASK);
        f2 += (int)((p >> 42) & FMASK);
    }
    float4 self = xs[i];
    int degE = (int)self.w;
    const float inv = 1.0f / FSCALE;
    float a0 = (float)(f0 - FBIAS * degE) * inv + self.x;
    float a1 = (float)(f1 - FBIAS * degE) * inv + self.y;
    float a2 = (float)(f2 - FBIAS * degE) * inv + self.z;
    float di = dinv[i];
    a0 *= di; a1 *= di; a2 *= di;
    float g = 0.0f;
#pragma unroll
    for (int c = 0; c < 16; ++c) {   // W1 [3,16] row-major
        float h = fmaf(a0, W1[c], fmaf(a1, W1[16 + c], fmaf(a2, W1[32 + c], b1[c])));
        h = fmaxf(h, 0.0f);
        g = fmaf(h, W2[c], g);
    }
    gs[i] = g * di;   // pre-scaled by dinv for layer-2 src side
}

// ---- layer 2 with last-block fixup (sigmoid epilogue in-kernel) ----
__global__ void k_agg2F2(const unsigned int* __restrict__ bin, const int* __restrict__ cursor,
                         const float* __restrict__ gs, const float* __restrict__ dinv,
                         float* __restrict__ part, int* __restrict__ done,
                         const float* __restrict__ b2, float* __restrict__ out,
                         int cap, int n) {
    __shared__ float facc[NPB];
    __shared__ int lastFlag;
    const int tid = threadIdx.x;
    facc[tid] = 0.0f;
    __syncthreads();
    const int bk = blockIdx.x >> 3;
    const int sub = blockIdx.x & (SPLIT - 1);
    const int cnt = min(cursor[bk], cap);
    int lo, hi; sub_range(cnt, sub, &lo, &hi);
    const unsigned int* bp = bin + (long long)bk * cap;
    const int len = hi - lo, nvec = len >> 2;
    const uint4* bp4 = (const uint4*)(bp + lo);
    for (int v = tid; v < nvec; v += T2) {
        uint4 q = bp4[v];
        float g0 = gs[q.x & 0x1FFFFu];
        float g1 = gs[q.y & 0x1FFFFu];
        float g2 = gs[q.z & 0x1FFFFu];
        float g3 = gs[q.w & 0x1FFFFu];
        atomicAdd(&facc[q.x >> 17], g0);
        atomicAdd(&facc[q.y >> 17], g1);
        atomicAdd(&facc[q.z >> 17], g2);
        atomicAdd(&facc[q.w >> 17], g3);
    }
    for (int k = lo + (nvec << 2) + tid; k < hi; k += T2)
        atomicAdd(&facc[bp[k] >> 17], gs[bp[k] & 0x1FFFFu]);
    __syncthreads();
    part[(long long)blockIdx.x * NPB + tid] = facc[tid];
    __threadfence();
    if (tid == 0) lastFlag = (atomicAdd(&done[bk], 1) == SPLIT - 1);
    __syncthreads();
    if (!lastFlag) return;
    __threadfence();
    const int i = bk * NPB + tid;
    if (i >= n) return;
    const volatile float* vp = part;
    float acc2 = gs[i];   // self-loop
#pragma unroll
    for (int s = 0; s < SPLIT; ++s)
        acc2 += vp[(long long)(bk * SPLIT + s) * NPB + tid];
    float z = dinv[i] * acc2 + b2[0];
    out[i] = 1.0f / (1.0f + expf(-z));
}

// ---------------- R1 fallback (small ws) ----------------
__global__ void k_detect(const int* e32, int* flag) {
    if (blockIdx.x == 0 && threadIdx.x == 0) {
        int is64 = 1;
        for (int k = 0; k < 16; ++k)
            if (e32[2 * k + 1] != 0) { is64 = 0; break; }
        *flag = is64;
    }
}
__global__ void f_init_deg(float* deg, int n) {
    int i = blockIdx.x * blockDim.x + threadIdx.x;
    if (i < n) deg[i] = 1.0f;
}
__global__ void f_deg(const void* edges, const int* flag, float* deg, long long E) {
    int is64 = *flag;
    long long e = (long long)blockIdx.x * blockDim.x + threadIdx.x;
    if (e < E) atomicAdd(&deg[load_idx(edges, E + e, is64)], 1.0f);
}
__global__ void f_dinv_xs(const float* x, const float* deg, float* dinv, float4* xs,
                          float4* agg3, int n) {
    int i = blockIdx.x * blockDim.x + threadIdx.x;
    if (i < n) {
        float di = rsqrtf(deg[i]);
        dinv[i] = di;
        float4 v = make_float4(x[3 * i] * di, x[3 * i + 1] * di, x[3 * i + 2] * di, 0.0f);
        xs[i] = v; agg3[i] = v;
    }
}
__global__ void f_edge1(const void* edges, const int* flag, const float4* xs,
                        float* agg3, long long E) {
    int is64 = *flag;
    long long e = (long long)blockIdx.x * blockDim.x + threadIdx.x;
    if (e < E) {
        long long s = load_idx(edges, e, is64);
        long long d = load_idx(edges, E + e, is64);
        float4 v = xs[s];
        atomicAdd(&agg3[4 * d + 0], v.x);
        atomicAdd(&agg3[4 * d + 1], v.y);
        atomicAdd(&agg3[4 * d + 2], v.z);
    }
}
__global__ void f_node1(const float* dinv, const float4* agg3, const float* W1,
                        const float* b1, const float* W2, float* gs, float* agg1, int n) {
    int i = blockIdx.x * blockDim.x + threadIdx.x;
    if (i < n) {
        float di = dinv[i];
        float4 a = agg3[i];
        float a0 = a.x * di, a1 = a.y * di, a2 = a.z * di;
        float g = 0.0f;
#pragma unroll
        for (int k = 0; k < 16; ++k) {
            float h = fmaf(a0, W1[k], fmaf(a1, W1[16 + k], fmaf(a2, W1[32 + k], b1[k])));
            h = fmaxf(h, 0.0f);
            g = fmaf(h, W2[k], g);
        }
        float v = g * di;
        gs[i] = v; agg1[i] = v;
    }
}
__global__ void f_edge2(const void* edges, const int* flag, const float* gs,
                        float* agg1, long long E) {
    int is64 = *flag;
    long long e = (long long)blockIdx.x * blockDim.x + threadIdx.x;
    if (e < E) atomicAdd(&agg1[load_idx(edges, E + e, is64)], gs[load_idx(edges, e, is64)]);
}
__global__ void f_final(const float* dinv, const float* agg1, const float* b2,
                        float* out, int n) {
    int i = blockIdx.x * blockDim.x + threadIdx.x;
    if (i < n) {
        float z = dinv[i] * agg1[i] + b2[0];
        out[i] = 1.0f / (1.0f + expf(-z));
    }
}

extern "C" void kernel_launch(void* const* d_in, const int* in_sizes, int n_in,
                              void* d_out, int out_size, void* d_ws, size_t ws_size,
                              hipStream_t stream) {
    const float* x  = (const float*)d_in[0];
    const void*  ei = d_in[1];
    const float* W1 = (const float*)d_in[2];
    const float* b1 = (const float*)d_in[3];
    const float* W2 = (const float*)d_in[4];
    const float* b2 = (const float*)d_in[5];
    float* out = (float*)d_out;

    const long long n = in_sizes[0] / 3;   // 100000
    const long long E = in_sizes[1] / 2;   // 3200000

    const int T = 256;
    const int gN = (int)((n + T - 1) / T);
    const int gE = (int)((E + T - 1) / T);

    const int nb = (int)((n + NPB - 1) / NPB);                       // 391
    long long capll = (E / nb) + (E / nb) / 8 + 256;                 // mean + ~11 sigma
    const int cap = (int)((capll + 63) / 64 * 64);

    size_t need = n * sizeof(float4)                                 // xs
                + (size_t)nb * SPLIT * NPB * sizeof(unsigned long long) // part (u64 worst)
                + (size_t)nb * cap * sizeof(int)                     // bin
                + 2 * n * sizeof(float)                              // dinv, gs
                + 4 * nb * sizeof(int) + 128;                        // cursor, done[3nb], flag

    if (nb <= NB_MAX && n <= (1 << 17) && ws_size >= need) {
        char* p = (char*)d_ws;
        float4* xs   = (float4*)p;            p += n * sizeof(float4);
        char*  partb = p;                     p += (size_t)nb * SPLIT * NPB * sizeof(unsigned long long);
        unsigned int* bin = (unsigned int*)p; p += (size_t)nb * cap * sizeof(int);
        float* dinv  = (float*)p;             p += n * sizeof(float);
        float* gs    = (float*)p;             p += n * sizeof(float);
        int*   cursor = (int*)p;              p += nb * sizeof(int);
        int*   done  = (int*)p;               p += 3 * nb * sizeof(int);
        int*   flag  = (int*)p;

        const long long per_blk = (long long)T1 * EPT;               // 2048 edges/block
        const int gB = (int)((E + per_blk - 1) / per_blk);           // 1563

        k_zf<<<(3 * nb + T - 1) / T, T, 0, stream>>>(cursor, done, nb, (const int*)ei, flag);
        k_bin<<<gB, T1, 0, stream>>>(ei, flag, cursor, bin, E, nb, cap);
        k_degF2<<<nb * SPLIT, T2, 0, stream>>>(bin, cursor, x, (int*)partb, done,
                                               dinv, xs, cap, (int)n);
        k_agg1F2<<<nb * SPLIT, T2, 0, stream>>>(bin, cursor, xs, dinv,
                                                (unsigned long long*)partb, done + nb,
                                                W1, b1, W2, gs, cap, (int)n);
        k_agg2F2<<<nb * SPLIT, T2, 0, stream>>>(bin, cursor, gs, dinv,
                                                (float*)partb, done + 2 * nb,
                                                b2, out, cap, (int)n);
    } else {
        // R1 proven atomic pipeline
        char* p = (char*)d_ws;
        float*  deg  = (float*)p;  p += n * sizeof(float);
        float*  dinv = (float*)p;  p += n * sizeof(float);
        float4* xs   = (float4*)p; p += n * sizeof(float4);
        float4* agg3 = (float4*)p; p += n * sizeof(float4);
        float*  gs   = (float*)p;  p += n * sizeof(float);
        float*  agg1 = (float*)p;  p += n * sizeof(float);
        int*    flag = (int*)p;

        k_detect<<<1, 64, 0, stream>>>((const int*)ei, flag);
        f_init_deg<<<gN, T, 0, stream>>>(deg, (int)n);
        f_deg<<<gE, T, 0, stream>>>(ei, flag, deg, E);
        f_dinv_xs<<<gN, T, 0, stream>>>(x, deg, dinv, xs, agg3, (int)n);
        f_edge1<<<gE, T, 0, stream>>>(ei, flag, xs, (float*)agg3, E);
        f_node1<<<gN, T, 0, stream>>>(dinv, agg3, W1, b1, W2, gs, agg1, (int)n);
        f_edge2<<<gE, T, 0, stream>>>(ei, flag, gs, agg1, E);
        f_final<<<gN, T, 0, stream>>>(dinv, agg1, b2, out, (int)n);
    }
}

// Round 6
// 147.608 us; speedup vs baseline: 8.1226x; 8.1226x over previous
//
#include <hip/hip_runtime.h>
#include <math.h>

// GCN 2-layer. R15 = R13 (151us proven) with balanced grids.
// R14's last-block fixup REVERTED: __threadfence (device scope) costs ~L2
// writeback x 3128 blocks on 8-XCD MI355X -> 445us in one kernel. Never again.
// R13's flaw: nb=391 co-resident blocks on 256 CUs -> static partition, max
// CU load = 2 buckets = 16384 edges (+31% over mean) on every heavy kernel.
// R15: NPB=200 -> nb=500 blocks (244 CUs x2 = 12800 edges max, +2.4%);
// bucket = dst/200 via exact magic division ((dst>>3)*85899346)>>31 (exact
// for dst < 2^17); local = dst - 200*bk <= 199 fits the 8-bit packed field.
// k_bin: EPT=13, gB=481 (max 2 tiles = 13312 edges, +6%).
// Predict 151 -> ~125-135us, absmax unchanged 0.0039. If ~150, imbalance is
// refuted -> stall is per-edge latency, go occupancy/cooperative next.

#define NPB 200        // nodes per bucket (NOT power of 2; chosen so nb=500)
#define NB_MAX 512     // max buckets supported by LDS arrays in k_bin
#define T1 512         // threads per block in k_bin
#define EPT 13         // edges staged per thread in k_bin (tile = 6656 edges)
#define T2 512         // threads per block in fused bucket kernels

#define FSCALE 1024.0f     // fixed-point scale (2^10)
#define FBIAS  8192        // per-addend bias (2^13)
#define FMASK  0x1FFFFFu   // 21-bit field mask

// bucket = d / 200 = (d>>3) / 25, exact for d < 2^17 via magic multiply
static __device__ __forceinline__ unsigned bucket_of(unsigned d) {
    unsigned m = d >> 3;
    return (unsigned)(((unsigned long long)m * 85899346ull) >> 31);
}

static __device__ __forceinline__ long long load_idx(const void* edges, long long pos, int is64) {
    if (is64) return ((const long long*)edges)[pos];
    return (long long)((const int*)edges)[pos];
}

static __device__ __forceinline__ unsigned long long pack3(float x, float y, float z) {
    unsigned long long e0 = (unsigned)(__float2int_rn(x * FSCALE) + FBIAS);
    unsigned long long e1 = (unsigned)(__float2int_rn(y * FSCALE) + FBIAS);
    unsigned long long e2 = (unsigned)(__float2int_rn(z * FSCALE) + FBIAS);
    return e0 | (e1 << 21) | (e2 << 42);
}

// zero cursors + dtype-detect flag (merged)
__global__ void k_zf(int* cursor, int nb, const int* e32, int* flag) {
    int i = blockIdx.x * blockDim.x + threadIdx.x;
    if (i < nb) cursor[i] = 0;
    if (i == 0) {
        int is64 = 1;
        for (int k = 0; k < 16; ++k)
            if (e32[2 * k + 1] != 0) { is64 = 0; break; }
        *flag = is64;
    }
}

// Register-staged binning: ONE pass over the edge list; 1 LDS atomic/edge
// (the histogram atomic's return value doubles as the placement rank).
__global__ void k_bin(const void* edges, const int* __restrict__ flag,
                      int* __restrict__ cursor, unsigned int* __restrict__ bin,
                      long long E, int nb, int cap) {
    __shared__ int hist[NB_MAX];
    __shared__ int base[NB_MAX];
    const int tid = threadIdx.x;
    for (int b = tid; b < nb; b += T1) hist[b] = 0;
    __syncthreads();

    const int is64 = *flag;
    const long long start = (long long)blockIdx.x * ((long long)T1 * EPT);
    unsigned es[EPT], ed[EPT];
    int rank[EPT];

    if (is64) {
        const long long* e64 = (const long long*)edges;
#pragma unroll
        for (int j = 0; j < EPT; ++j) {
            long long e = start + j * T1 + tid;
            if (e < E) { es[j] = (unsigned)e64[e]; ed[j] = (unsigned)e64[E + e]; }
            else ed[j] = 0xFFFFFFFFu;
        }
    } else {
        const int* e32 = (const int*)edges;
#pragma unroll
        for (int j = 0; j < EPT; ++j) {
            long long e = start + j * T1 + tid;
            if (e < E) { es[j] = (unsigned)e32[e]; ed[j] = (unsigned)e32[E + e]; }
            else ed[j] = 0xFFFFFFFFu;
        }
    }

#pragma unroll
    for (int j = 0; j < EPT; ++j)
        if (ed[j] != 0xFFFFFFFFu)
            rank[j] = atomicAdd(&hist[bucket_of(ed[j])], 1);
    __syncthreads();

    for (int b = tid; b < nb; b += T1) {
        int h = hist[b];
        base[b] = h ? atomicAdd(&cursor[b], h) : 0;
    }
    __syncthreads();

#pragma unroll
    for (int j = 0; j < EPT; ++j) {
        if (ed[j] == 0xFFFFFFFFu) continue;
        unsigned bk = bucket_of(ed[j]);
        unsigned loc = ed[j] - bk * NPB;           // < 200, fits 8 bits
        int off = base[bk] + rank[j];
        if (off < cap)
            bin[(long long)bk * cap + off] = (loc << 17) | es[j];
    }
}

// ---- fused degree: one block per bucket; LDS count + dinv/xs epilogue ----
__global__ void k_degF(const unsigned int* __restrict__ bin, const int* __restrict__ cursor,
                       const float* __restrict__ x, float* __restrict__ dinv,
                       float4* __restrict__ xs, int cap, int n) {
    __shared__ int dcnt[NPB];
    const int tid = threadIdx.x;
    if (tid < NPB) dcnt[tid] = 0;
    __syncthreads();
    const int bk = blockIdx.x;
    const int cnt = min(cursor[bk], cap);
    const unsigned int* bp = bin + (long long)bk * cap;
    const int nvec = cnt >> 2;
    const uint4* bp4 = (const uint4*)bp;
    for (int v = tid; v < nvec; v += T2) {
        uint4 q = bp4[v];
        atomicAdd(&dcnt[q.x >> 17], 1);
        atomicAdd(&dcnt[q.y >> 17], 1);
        atomicAdd(&dcnt[q.z >> 17], 1);
        atomicAdd(&dcnt[q.w >> 17], 1);
    }
    for (int k = (nvec << 2) + tid; k < cnt; k += T2)
        atomicAdd(&dcnt[bp[k] >> 17], 1);
    __syncthreads();
    if (tid < NPB) {
        const int i = bk * NPB + tid;
        if (i < n) {
            int degE = dcnt[tid];
            float di = rsqrtf((float)degE + 1.0f);
            dinv[i] = di;
            xs[i] = make_float4(x[3 * i] * di, x[3 * i + 1] * di, x[3 * i + 2] * di, (float)degE);
        }
    }
}

// ---- fused layer 1: one block per bucket; u64 packed LDS accumulate +
// decode/MLP epilogue. Per-node sums stay in 21-bit fields. ----
__global__ void k_agg1FU(const unsigned int* __restrict__ bin, const int* __restrict__ cursor,
                         const float4* __restrict__ xs, const float* __restrict__ dinv,
                         const float* __restrict__ W1, const float* __restrict__ b1,
                         const float* __restrict__ W2, float* __restrict__ gs,
                         int cap, int n) {
    __shared__ unsigned long long acc[NPB];
    const int tid = threadIdx.x;
    if (tid < NPB) acc[tid] = 0ull;
    __syncthreads();
    const int bk = blockIdx.x;
    const int cnt = min(cursor[bk], cap);
    const unsigned int* bp = bin + (long long)bk * cap;
    const int nvec = cnt >> 2;
    const uint4* bp4 = (const uint4*)bp;
    for (int v = tid; v < nvec; v += T2) {
        uint4 q = bp4[v];
        float4 v0 = xs[q.x & 0x1FFFFu];
        float4 v1 = xs[q.y & 0x1FFFFu];
        float4 v2 = xs[q.z & 0x1FFFFu];
        float4 v3 = xs[q.w & 0x1FFFFu];
        atomicAdd(&acc[q.x >> 17], pack3(v0.x, v0.y, v0.z));
        atomicAdd(&acc[q.y >> 17], pack3(v1.x, v1.y, v1.z));
        atomicAdd(&acc[q.z >> 17], pack3(v2.x, v2.y, v2.z));
        atomicAdd(&acc[q.w >> 17], pack3(v3.x, v3.y, v3.z));
    }
    for (int k = (nvec << 2) + tid; k < cnt; k += T2) {
        unsigned p = bp[k];
        float4 v = xs[p & 0x1FFFFu];
        atomicAdd(&acc[p >> 17], pack3(v.x, v.y, v.z));
    }
    __syncthreads();
    if (tid < NPB) {
        const int i = bk * NPB + tid;
        if (i < n) {
            unsigned long long p = acc[tid];
            int f0 = (int)(p & FMASK);
            int f1 = (int)((p >> 21) & FMASK);
            int f2 = (int)((p >> 42) & FMASK);
            float4 self = xs[i];
            int degE = (int)self.w;
            const float inv = 1.0f / FSCALE;
            float a0 = (float)(f0 - FBIAS * degE) * inv + self.x;
            float a1 = (float)(f1 - FBIAS * degE) * inv + self.y;
            float a2 = (float)(f2 - FBIAS * degE) * inv + self.z;
            float di = dinv[i];
            a0 *= di; a1 *= di; a2 *= di;
            float g = 0.0f;
#pragma unroll
            for (int c = 0; c < 16; ++c) {   // W1 [3,16] row-major
                float h = fmaf(a0, W1[c], fmaf(a1, W1[16 + c], fmaf(a2, W1[32 + c], b1[c])));
                h = fmaxf(h, 0.0f);
                g = fmaf(h, W2[c], g);
            }
            gs[i] = g * di;   // pre-scaled by dinv for layer-2 src side
        }
    }
}

// ---- fused layer 2: one block per bucket; f32 LDS accumulate + sigmoid ----
__global__ void k_agg2FU(const unsigned int* __restrict__ bin, const int* __restrict__ cursor,
                         const float* __restrict__ gs, const float* __restrict__ dinv,
                         const float* __restrict__ b2, float* __restrict__ out,
                         int cap, int n) {
    __shared__ float facc[NPB];
    const int tid = threadIdx.x;
    if (tid < NPB) facc[tid] = 0.0f;
    __syncthreads();
    const int bk = blockIdx.x;
    const int cnt = min(cursor[bk], cap);
    const unsigned int* bp = bin + (long long)bk * cap;
    const int nvec = cnt >> 2;
    const uint4* bp4 = (const uint4*)bp;
    for (int v = tid; v < nvec; v += T2) {
        uint4 q = bp4[v];
        float g0 = gs[q.x & 0x1FFFFu];
        float g1 = gs[q.y & 0x1FFFFu];
        float g2 = gs[q.z & 0x1FFFFu];
        float g3 = gs[q.w & 0x1FFFFu];
        atomicAdd(&facc[q.x >> 17], g0);
        atomicAdd(&facc[q.y >> 17], g1);
        atomicAdd(&facc[q.z >> 17], g2);
        atomicAdd(&facc[q.w >> 17], g3);
    }
    for (int k = (nvec << 2) + tid; k < cnt; k += T2)
        atomicAdd(&facc[bp[k] >> 17], gs[bp[k] & 0x1FFFFu]);
    __syncthreads();
    if (tid < NPB) {
        const int i = bk * NPB + tid;
        if (i < n) {
            float z = dinv[i] * (facc[tid] + gs[i]) + b2[0];
            out[i] = 1.0f / (1.0f + expf(-z));
        }
    }
}

// ---------------- R1 fallback (small ws) ----------------
__global__ void k_detect(const int* e32, int* flag) {
    if (blockIdx.x == 0 && threadIdx.x == 0) {
        int is64 = 1;
        for (int k = 0; k < 16; ++k)
            if (e32[2 * k + 1] != 0) { is64 = 0; break; }
        *flag = is64;
    }
}
__global__ void f_init_deg(float* deg, int n) {
    int i = blockIdx.x * blockDim.x + threadIdx.x;
    if (i < n) deg[i] = 1.0f;
}
__global__ void f_deg(const void* edges, const int* flag, float* deg, long long E) {
    int is64 = *flag;
    long long e = (long long)blockIdx.x * blockDim.x + threadIdx.x;
    if (e < E) atomicAdd(&deg[load_idx(edges, E + e, is64)], 1.0f);
}
__global__ void f_dinv_xs(const float* x, const float* deg, float* dinv, float4* xs,
                          float4* agg3, int n) {
    int i = blockIdx.x * blockDim.x + threadIdx.x;
    if (i < n) {
        float di = rsqrtf(deg[i]);
        dinv[i] = di;
        float4 v = make_float4(x[3 * i] * di, x[3 * i + 1] * di, x[3 * i + 2] * di, 0.0f);
        xs[i] = v; agg3[i] = v;
    }
}
__global__ void f_edge1(const void* edges, const int* flag, const float4* xs,
                        float* agg3, long long E) {
    int is64 = *flag;
    long long e = (long long)blockIdx.x * blockDim.x + threadIdx.x;
    if (e < E) {
        long long s = load_idx(edges, e, is64);
        long long d = load_idx(edges, E + e, is64);
        float4 v = xs[s];
        atomicAdd(&agg3[4 * d + 0], v.x);
        atomicAdd(&agg3[4 * d + 1], v.y);
        atomicAdd(&agg3[4 * d + 2], v.z);
    }
}
__global__ void f_node1(const float* dinv, const float4* agg3, const float* W1,
                        const float* b1, const float* W2, float* gs, float* agg1, int n) {
    int i = blockIdx.x * blockDim.x + threadIdx.x;
    if (i < n) {
        float di = dinv[i];
        float4 a = agg3[i];
        float a0 = a.x * di, a1 = a.y * di, a2 = a.z * di;
        float g = 0.0f;
#pragma unroll
        for (int k = 0; k < 16; ++k) {
            float h = fmaf(a0, W1[k], fmaf(a1, W1[16 + k], fmaf(a2, W1[32 + k], b1[k])));
            h = fmaxf(h, 0.0f);
            g = fmaf(h, W2[k], g);
        }
        float v = g * di;
        gs[i] = v; agg1[i] = v;
    }
}
__global__ void f_edge2(const void* edges, const int* flag, const float* gs,
                        float* agg1, long long E) {
    int is64 = *flag;
    long long e = (long long)blockIdx.x * blockDim.x + threadIdx.x;
    if (e < E) atomicAdd(&agg1[load_idx(edges, E + e, is64)], gs[load_idx(edges, e, is64)]);
}
__global__ void f_final(const float* dinv, const float* agg1, const float* b2,
                        float* out, int n) {
    int i = blockIdx.x * blockDim.x + threadIdx.x;
    if (i < n) {
        float z = dinv[i] * agg1[i] + b2[0];
        out[i] = 1.0f / (1.0f + expf(-z));
    }
}

extern "C" void kernel_launch(void* const* d_in, const int* in_sizes, int n_in,
                              void* d_out, int out_size, void* d_ws, size_t ws_size,
                              hipStream_t stream) {
    const float* x  = (const float*)d_in[0];
    const void*  ei = d_in[1];
    const float* W1 = (const float*)d_in[2];
    const float* b1 = (const float*)d_in[3];
    const float* W2 = (const float*)d_in[4];
    const float* b2 = (const float*)d_in[5];
    float* out = (float*)d_out;

    const long long n = in_sizes[0] / 3;   // 100000
    const long long E = in_sizes[1] / 2;   // 3200000

    const int T = 256;
    const int gN = (int)((n + T - 1) / T);
    const int gE = (int)((E + T - 1) / T);

    const int nb = (int)((n + NPB - 1) / NPB);                       // 500
    long long capll = (E / nb) + (E / nb) / 8 + 256;                 // mean + ~13 sigma
    const int cap = (int)((capll + 63) / 64 * 64);

    size_t need = n * sizeof(float4)                                 // xs
                + (size_t)nb * cap * sizeof(int)                     // bin
                + 2 * n * sizeof(float)                              // dinv, gs
                + nb * sizeof(int) + 128;                            // cursor, flag

    // magic division assumes dst < 2^17 and NPB==200; packing needs n <= 2^17
    if (nb <= NB_MAX && n <= 102400 && ws_size >= need) {
        char* p = (char*)d_ws;
        float4* xs   = (float4*)p;            p += n * sizeof(float4);
        unsigned int* bin = (unsigned int*)p; p += (size_t)nb * cap * sizeof(int);
        float* dinv  = (float*)p;             p += n * sizeof(float);
        float* gs    = (float*)p;             p += n * sizeof(float);
        int*   cursor = (int*)p;              p += nb * sizeof(int);
        int*   flag  = (int*)p;

        const long long per_blk = (long long)T1 * EPT;               // 6656 edges/block
        const int gB = (int)((E + per_blk - 1) / per_blk);           // 481

        k_zf<<<(nb + T - 1) / T, T, 0, stream>>>(cursor, nb, (const int*)ei, flag);
        k_bin<<<gB, T1, 0, stream>>>(ei, flag, cursor, bin, E, nb, cap);
        k_degF<<<nb, T2, 0, stream>>>(bin, cursor, x, dinv, xs, cap, (int)n);
        k_agg1FU<<<nb, T2, 0, stream>>>(bin, cursor, xs, dinv, W1, b1, W2, gs, cap, (int)n);
        k_agg2FU<<<nb, T2, 0, stream>>>(bin, cursor, gs, dinv, b2, out, cap, (int)n);
    } else {
        // R1 proven atomic pipeline
        char* p = (char*)d_ws;
        float*  deg  = (float*)p;  p += n * sizeof(float);
        float*  dinv = (float*)p;  p += n * sizeof(float);
        float4* xs   = (float4*)p; p += n * sizeof(float4);
        float4* agg3 = (float4*)p; p += n * sizeof(float4);
        float*  gs   = (float*)p;  p += n * sizeof(float);
        float*  agg1 = (float*)p;  p += n * sizeof(float);
        int*    flag = (int*)p;

        k_detect<<<1, 64, 0, stream>>>((const int*)ei, flag);
        f_init_deg<<<gN, T, 0, stream>>>(deg, (int)n);
        f_deg<<<gE, T, 0, stream>>>(ei, flag, deg, E);
        f_dinv_xs<<<gN, T, 0, stream>>>(x, deg, dinv, xs, agg3, (int)n);
        f_edge1<<<gE, T, 0, stream>>>(ei, flag, xs, (float*)agg3, E);
        f_node1<<<gN, T, 0, stream>>>(dinv, agg3, W1, b1, W2, gs, agg1, (int)n);
        f_edge2<<<gE, T, 0, stream>>>(ei, flag, gs, agg1, E);
        f_final<<<gN, T, 0, stream>>>(dinv, agg1, b2, out, (int)n);
    }
}